// Round 6
// baseline (211.679 us; speedup 1.0000x reference)
//
#include <hip/hip_runtime.h>
#include <hip/hip_bf16.h>

// B=4, S=1024, E=1024, H=16, d=64 -> NH=64 heads. Out: [64,1024,1024] fp32.
// sparsemax(Q K^T) per head, SCALE=1.0. V chunk of the projection is dead.

typedef __attribute__((ext_vector_type(8))) short bf16x8;   // 8 bf16 = 4 VGPRs
typedef __attribute__((ext_vector_type(4))) float f32x4;

__device__ __forceinline__ ushort f2bf(float x) {           // RNE f32 -> bf16 bits
    uint u = __float_as_uint(x);
    u += 0x7FFFu + ((u >> 16) & 1u);
    return (ushort)(u >> 16);
}
__device__ __forceinline__ float bf2f(ushort h) {
    return __uint_as_float(((uint)h) << 16);
}

typedef const __attribute__((address_space(1))) unsigned int* gptr_t;
typedef __attribute__((address_space(3))) unsigned int* sptr_t;
__device__ __forceinline__ void gload_lds16(const void* g, void* l) {
    __builtin_amdgcn_global_load_lds((gptr_t)g, (sptr_t)l, 16, 0, 0);
}

// ---------------------------------------------------------------------------
// Kernel 0: fp32 -> split bf16 (hi = bf16(v), lo = bf16(v - hi)), elementwise.
// ---------------------------------------------------------------------------
__global__ __launch_bounds__(256)
void convert_split_kernel(const float* __restrict__ in, ushort* __restrict__ hi,
                          ushort* __restrict__ lo, int n4)
{
    int i = blockIdx.x * 256 + threadIdx.x;
    const int stride = gridDim.x * 256;
    for (; i < n4; i += stride) {
        float4 v = ((const float4*)in)[i];
        ushort4 h, l;
        h.x = f2bf(v.x); l.x = f2bf(v.x - bf2f(h.x));
        h.y = f2bf(v.y); l.y = f2bf(v.y - bf2f(h.y));
        h.z = f2bf(v.z); l.z = f2bf(v.z - bf2f(h.z));
        h.w = f2bf(v.w); l.w = f2bf(v.w - bf2f(h.w));
        ((ushort4*)hi)[i] = h;
        ((ushort4*)lo)[i] = l;
    }
}

// ---------------------------------------------------------------------------
// Kernel 1: projection GEMM via split-bf16 MFMA (unchanged from round 3).
// ---------------------------------------------------------------------------
__global__ __launch_bounds__(512)
void proj_kernel(const ushort* __restrict__ xh, const ushort* __restrict__ xl,
                 const ushort* __restrict__ wh, const ushort* __restrict__ wl,
                 ushort* __restrict__ khi, ushort* __restrict__ klo,
                 ushort* __restrict__ qhi, ushort* __restrict__ qlo)
{
    __shared__ __align__(16) ushort Ah[128 * 64], Al[128 * 64];   // 16 KB each
    __shared__ __align__(16) ushort Bh[128 * 64], Bl[128 * 64];   // total 64 KB
    const int tid = threadIdx.x, w = tid >> 6, l = tid & 63;
    const int m0 = blockIdx.y * 128, c0 = blockIdx.x * 128;
    const int wr = w >> 2, wc = w & 3;          // wave -> 64m x 32c sub-tile
    const int lm = l & 15, lk = l >> 4;
    const int sslot = (l & 7) ^ (l >> 3);       // pre-swizzled source chunk

    f32x4 acc[4][2];
#pragma unroll
    for (int mf = 0; mf < 4; ++mf)
#pragma unroll
        for (int nf = 0; nf < 2; ++nf) acc[mf][nf] = (f32x4){0.f, 0.f, 0.f, 0.f};

    for (int k0 = 0; k0 < 1024; k0 += 64) {
        __syncthreads();                        // prev ds_reads done
#pragma unroll
        for (int i = 0; i < 2; ++i) {
            const int r = 16 * w + 8 * i + (l >> 3);
            const size_t ga = (size_t)(m0 + r) * 1024 + k0 + sslot * 8;
            const size_t gb = (size_t)(c0 + r) * 1024 + k0 + sslot * 8;
            const int lb = (16 * w + 8 * i) * 128;          // LDS byte base (uniform)
            gload_lds16(xh + ga, (char*)Ah + lb);
            gload_lds16(xl + ga, (char*)Al + lb);
            gload_lds16(wh + gb, (char*)Bh + lb);
            gload_lds16(wl + gb, (char*)Bl + lb);
        }
        __syncthreads();                        // vmcnt drained by barrier
#pragma unroll
        for (int kc = 0; kc < 2; ++kc) {
            bf16x8 a_h[4], a_l[4], b_h[2], b_l[2];
#pragma unroll
            for (int mf = 0; mf < 4; ++mf) {
                const int ra = wr * 64 + mf * 16 + lm;
                const int off = ra * 128 + ((kc * 4 + lk) ^ (ra & 7)) * 16;
                a_h[mf] = *(const bf16x8*)((const char*)Ah + off);
                a_l[mf] = *(const bf16x8*)((const char*)Al + off);
            }
#pragma unroll
            for (int nf = 0; nf < 2; ++nf) {
                const int rb = wc * 32 + nf * 16 + lm;
                const int off = rb * 128 + ((kc * 4 + lk) ^ (rb & 7)) * 16;
                b_h[nf] = *(const bf16x8*)((const char*)Bh + off);
                b_l[nf] = *(const bf16x8*)((const char*)Bl + off);
            }
#pragma unroll
            for (int mf = 0; mf < 4; ++mf)
#pragma unroll
                for (int nf = 0; nf < 2; ++nf) {
                    f32x4 a = acc[mf][nf];
                    a = __builtin_amdgcn_mfma_f32_16x16x32_bf16(a_h[mf], b_h[nf], a, 0, 0, 0);
                    a = __builtin_amdgcn_mfma_f32_16x16x32_bf16(a_l[mf], b_h[nf], a, 0, 0, 0);
                    a = __builtin_amdgcn_mfma_f32_16x16x32_bf16(a_h[mf], b_l[nf], a, 0, 0, 0);
                    acc[mf][nf] = a;
                }
        }
    }

    // epilogue: split-bf16, scatter to head-major K / Q buffers
#pragma unroll
    for (int mf = 0; mf < 4; ++mf)
#pragma unroll
        for (int nf = 0; nf < 2; ++nf) {
            const int c = c0 + wc * 32 + nf * 16 + lm;
            const int cc = c & 1023;
            ushort* dh = (c < 1024) ? khi : qhi;
            ushort* dl = (c < 1024) ? klo : qlo;
#pragma unroll
            for (int rg = 0; rg < 4; ++rg) {
                const int m = m0 + wr * 64 + mf * 16 + lk * 4 + rg;
                const float v = acc[mf][nf][rg];
                const ushort h = f2bf(v), lo_ = f2bf(v - bf2f(h));
                const int nhd = ((m >> 10) << 4) + (cc >> 6);
                const size_t off = ((size_t)nhd << 16) + ((size_t)(m & 1023) << 6) + (cc & 63);
                dh[off] = h;
                dl[off] = lo_;
            }
        }
}

// ---------------------------------------------------------------------------
// Kernel 2: fused logits MFMA-GEMM + sparsemax.
// Round-6 change: 1024 threads (16 waves) on the SAME 16-row tile.
//   - LDS unchanged (65.8 KB -> 2 blocks/CU) but waves/CU 13 -> 32
//     (8 waves/SIMD): the dependent chains (K loads, shuffle butterflies,
//     Michelot passes) now overlap across 2.5x more waves.
//   - Wave wv computes the 16x64 logit strip at cols wv*64 (4 nf iters,
//     24 MFMAs, depth-1 prefetch), then owns sparsemax row wv alone.
//   - __launch_bounds__(1024, 8) pins VGPR <= 64 for 8 waves/SIMD.
// Kept: XCD-chunked swizzle, NT output stores, tau0 = rowmax-1 Michelot.
// ---------------------------------------------------------------------------
__global__ __launch_bounds__(1024, 8)
void attn_sparsemax_kernel(const ushort* __restrict__ khi, const ushort* __restrict__ klo,
                           const ushort* __restrict__ qhi, const ushort* __restrict__ qlo,
                           float* __restrict__ out)
{
    __shared__ __align__(16) float lg[16][1028];   // 65792 B
    const int tid = threadIdx.x, wv = tid >> 6, ln = tid & 63;   // wv 0..15
    const int bid = blockIdx.y * gridDim.x + blockIdx.x;     // linear dispatch id
    const int vb  = (bid & 7) * 512 + (bid >> 3);            // XCD-chunked remap
    const int n   = vb >> 6;                                 // head 0..63
    const int r0  = (vb & 63) << 4;                          // q-row base
    const size_t hb = (size_t)n << 16;                       // head base, elems
    const int lm = ln & 15, lk = ln >> 4;

    // A fragments: Q rows r0 + lm, d = kc*32 + lk*8 + j (16B/lane)
    bf16x8 qh[2], ql[2];
#pragma unroll
    for (int kc = 0; kc < 2; ++kc) {
        const size_t o = hb + ((size_t)(r0 + lm) << 6) + kc * 32 + lk * 8;
        qh[kc] = *(const bf16x8*)(qhi + o);
        ql[kc] = *(const bf16x8*)(qlo + o);
    }

    f32x4 acc[4];
#pragma unroll
    for (int nf = 0; nf < 4; ++nf) acc[nf] = (f32x4){0.f, 0.f, 0.f, 0.f};

    const int c0 = wv * 64;                     // this wave's 64-col strip
    // hoisted base: fragment nf lives at Kh + nf*1024 elems (+32 second d-half)
    const ushort* Kh = khi + hb + (((size_t)(c0 + lm)) << 6) + lk * 8;
    const ushort* Kl = klo + hb + (((size_t)(c0 + lm)) << 6) + lk * 8;

    bf16x8 ch0 = *(const bf16x8*)(Kh);
    bf16x8 ch1 = *(const bf16x8*)(Kh + 32);
    bf16x8 cl0 = *(const bf16x8*)(Kl);
    bf16x8 cl1 = *(const bf16x8*)(Kl + 32);
#pragma unroll
    for (int nf = 0; nf < 4; ++nf) {
        bf16x8 nh0, nh1, nl0, nl1;
        if (nf < 3) {                           // prefetch next fragment set
            const ushort* ph = Kh + ((nf + 1) << 10);
            const ushort* pl = Kl + ((nf + 1) << 10);
            nh0 = *(const bf16x8*)(ph);
            nh1 = *(const bf16x8*)(ph + 32);
            nl0 = *(const bf16x8*)(pl);
            nl1 = *(const bf16x8*)(pl + 32);
        }
        f32x4 a = acc[nf];
        a = __builtin_amdgcn_mfma_f32_16x16x32_bf16(qh[0], ch0, a, 0, 0, 0);
        a = __builtin_amdgcn_mfma_f32_16x16x32_bf16(qh[1], ch1, a, 0, 0, 0);
        a = __builtin_amdgcn_mfma_f32_16x16x32_bf16(ql[0], ch0, a, 0, 0, 0);
        a = __builtin_amdgcn_mfma_f32_16x16x32_bf16(ql[1], ch1, a, 0, 0, 0);
        a = __builtin_amdgcn_mfma_f32_16x16x32_bf16(qh[0], cl0, a, 0, 0, 0);
        a = __builtin_amdgcn_mfma_f32_16x16x32_bf16(qh[1], cl1, a, 0, 0, 0);
        acc[nf] = a;
        if (nf < 3) { ch0 = nh0; ch1 = nh1; cl0 = nl0; cl1 = nl1; }
    }

    // scatter fragments to LDS logits (rows lk*4+rg, col lm-strip)
#pragma unroll
    for (int nf = 0; nf < 4; ++nf)
#pragma unroll
        for (int rg = 0; rg < 4; ++rg)
            lg[lk * 4 + rg][c0 + nf * 16 + lm] = acc[nf][rg];
    __syncthreads();

    // --- sparsemax: wave wv owns row wv ---
    float zz[16];
#pragma unroll
    for (int t = 0; t < 4; ++t) {
        float4 v = *(const float4*)&lg[wv][(ln << 2) + (t << 8)];
        zz[4 * t + 0] = v.x; zz[4 * t + 1] = v.y;
        zz[4 * t + 2] = v.z; zz[4 * t + 3] = v.w;
    }

    float mx = zz[0];
#pragma unroll
    for (int e = 1; e < 16; ++e) mx = fmaxf(mx, zz[e]);
#pragma unroll
    for (int o = 32; o > 0; o >>= 1) mx = fmaxf(mx, __shfl_xor(mx, o));

    // Michelot from tau0 = max-1 (valid: p_max <= 1 => tau* >= max-1;
    // monotone tau_t up to tau*, support shrinks; ~2-4 passes).
    float tau = mx - 1.0f;
    int kcur = 0;
    for (int it = 0; it < 64; ++it) {
        float sl = 0.f; int kl = 0;
#pragma unroll
        for (int e = 0; e < 16; ++e) {
            if (zz[e] > tau) { sl += zz[e]; ++kl; }
        }
#pragma unroll
        for (int o = 32; o > 0; o >>= 1) {
            sl += __shfl_xor(sl, o);
            kl += __shfl_xor(kl, o);
        }
        if (kl == kcur) break;         // support stable -> tau final
        kcur = kl;
        tau = (sl - 1.0f) / (float)kl;
    }

    float* orow = out + ((size_t)n * 1024 + (size_t)(r0 + wv)) * 1024;
#pragma unroll
    for (int t = 0; t < 4; ++t) {
        f32x4 o;
        o[0] = fmaxf(zz[4 * t + 0] - tau, 0.f);
        o[1] = fmaxf(zz[4 * t + 1] - tau, 0.f);
        o[2] = fmaxf(zz[4 * t + 2] - tau, 0.f);
        o[3] = fmaxf(zz[4 * t + 3] - tau, 0.f);
        __builtin_nontemporal_store(o, (f32x4*)&orow[(ln << 2) + (t << 8)]);
    }
}

// ---------------------------------------------------------------------------
extern "C" void kernel_launch(void* const* d_in, const int* in_sizes, int n_in,
                              void* d_out, int out_size, void* d_ws, size_t ws_size,
                              hipStream_t stream) {
    const float* x = (const float*)d_in[0];          // [4096, 1024]
    const float* w = (const float*)d_in[1];          // [3072, 1024]
    float* out = (float*)d_out;                      // [64, 1024, 1024]

    const size_t HE = (size_t)64 * 1024 * 64;        // 4.19M elems per head buf
    const size_t XE = (size_t)4096 * 1024;           // x elems
    const size_t WE = (size_t)2048 * 1024;           // W' elems (rows 1024..3071)
    ushort* khi = (ushort*)d_ws;
    ushort* klo = khi + HE;
    ushort* qhi = klo + HE;
    ushort* qlo = qhi + HE;
    ushort* xh  = qlo + HE;
    ushort* xl  = xh + XE;
    ushort* wh  = xl + XE;
    ushort* wl  = wh + WE;                           // total ~58.7 MB of d_ws

    convert_split_kernel<<<2048, 256, 0, stream>>>(x, xh, xl, (int)(XE / 4));
    convert_split_kernel<<<2048, 256, 0, stream>>>(w + (size_t)1024 * 1024, wh, wl, (int)(WE / 4));
    proj_kernel<<<dim3(16, 32), 512, 0, stream>>>(xh, xl, wh, wl, khi, klo, qhi, qlo);
    attn_sparsemax_kernel<<<dim3(64, 64), 1024, 0, stream>>>(khi, klo, qhi, qlo, out);
}